// Round 5
// baseline (693.724 us; speedup 1.0000x reference)
//
#include <hip/hip_runtime.h>

// 2-layer LSTM (H=50, B=4096, T=512, D_in=1) + FC(50->1), fused MFMA, round 5.
//
// 256 blocks (1/CU) x 512 threads (8 waves), 16 batches/block, all 512 steps.
// v_mfma_f32_16x16x32_bf16, hi/lo bf16 split, 3 products (~fp32 accuracy).
//
// KEY CHANGE vs round 4: WAVE SPECIALIZATION BY LAYER.
//   waves 0-3 (cls=0): layer-0 matvec+update for all 13 M-tiles (3-4 tiles/wave)
//   waves 4-7 (cls=1): layer-1 ditto.
// Same pipelined schedule as r4 (iter tt: layer0 at t=tt, layer1 at t=tt-1,
// both read ONE Hcat snapshot; single barrier per iteration; double-buffered
// H-fragments on parity tt&1). Wins:
//   - L0 waves read only ks0-1 (h1 half of Hcat): 48 instead of 64 b128/CU-iter
//   - 13 real tiles per class instead of 16 padded (r4 waves 5-7 ran dummies)
//   - per-SIMD wave pair has heterogeneous mix -> pipes overlap, not lockstep
//   - biases + W_ih0*x folded into MFMA accumulator init
// Gate-interleaved row permutation (r4-verified): packed row 4u+g -> lane
// (q,m) of tile T holds all 4 gates of unit 4T+q, batch m, in its 4 acc regs.
// B-frag layout (r2-r4-verified): k -> ks=k>>5, lane=((k>>3)&3)*16+n, j=k&7.

#define TT 512
#define HH 50
#define BT 16

typedef short short8 __attribute__((ext_vector_type(8)));
typedef float floatx4 __attribute__((ext_vector_type(4)));

static __device__ __forceinline__ float fast_sig(float x) {
    float e = __builtin_amdgcn_exp2f(x * -1.44269504f);   // exp(-x)
    return __builtin_amdgcn_rcpf(1.0f + e);
}
static __device__ __forceinline__ float fast_tanh(float x) {
    float e = __builtin_amdgcn_exp2f(x * -2.88539008f);   // exp(-2x)
    return __builtin_amdgcn_rcpf(1.0f + e) * 2.0f - 1.0f;
}
static __device__ __forceinline__ void split_bf16(float x, short& hi, short& lo) {
    unsigned u = __float_as_uint(x);
    hi = (short)(u >> 16);
    float xh = __uint_as_float(u & 0xffff0000u);
    lo = (short)(__float_as_uint(x - xh) >> 16);
}
#define MFMA(a, b, c) __builtin_amdgcn_mfma_f32_16x16x32_bf16((a), (b), (c), 0, 0, 0)

__global__ __launch_bounds__(512, 2) void lstm_mfma(
    const float* __restrict__ x,
    const float* __restrict__ W_ih0, const float* __restrict__ W_hh0,
    const float* __restrict__ b_ih0, const float* __restrict__ b_hh0,
    const float* __restrict__ W_ih1, const float* __restrict__ W_hh1,
    const float* __restrict__ b_ih1, const float* __restrict__ b_hh1,
    const float* __restrict__ W_fc,  const float* __restrict__ b_fc,
    float* __restrict__ out)
{
    __shared__ __align__(16) short Hhi[2][2048];   // [buf][(ks*64+lane)*8+j]
    __shared__ __align__(16) short Hlo[2][2048];
    __shared__ float xs[TT * BT];
    __shared__ float h2f[BT * HH];

    const int tid = threadIdx.x;
    const int ln  = tid & 63;
    const int wv  = tid >> 6;
    const int cls = wv >> 2;          // 0 = layer0 waves, 1 = layer1 waves
    const int wl  = wv & 3;           // wave index within class
    const int m   = ln & 15;          // batch col
    const int q   = ln >> 4;          // quad
    const int b0g = blockIdx.x * BT;

    // ---------------- one-time init ----------------
    for (int i = tid; i < BT * TT; i += 512) {
        int b = i & 15, t = i >> 4;
        xs[t * BT + b] = x[(size_t)(b0g + b) * TT + t];
    }
    for (int i = tid; i < 2 * 2048; i += 512) {
        ((short*)Hhi)[i] = 0; ((short*)Hlo)[i] = 0;
    }

    // ---- per-wave slots: s<3 -> tile wl+4s ; s==3 -> tile 12 (wl==0 only) ----
    short8 fh[4][4], fl[4][4];        // [slot][ks] A-frag hi/lo (this class's W)
    float  cc[4][4];                  // acc-init constants (bias per gate)
    float  bw[4][4];                  // W_ih0 per gate (cls 0) / 0 (cls 1)
    int    widx[4], uCs[4];
    bool   vC[4];
    float  cst[4] = {0.f, 0.f, 0.f, 0.f};   // c-state per slot

#pragma unroll
    for (int s = 0; s < 4; ++s) {
        const int  tile = (s < 3) ? (wl + 4 * s) : 12;
        const bool sv   = (s < 3) || (wl == 0);
        const int  uA   = 4 * tile + (m >> 2);
        const int  gA   = m & 3;
        const bool rokA = sv && (uA < HH);
        const int  wrow = gA * HH + uA;
#pragma unroll
        for (int ks = 0; ks < 4; ++ks) {
            short8 h8, l8;
#pragma unroll
            for (int j = 0; j < 8; ++j) {
                int k = ks * 32 + q * 8 + j;
                float w = 0.f;
                if (cls == 0) {
                    if (rokA && ks < 2 && k < HH) w = W_hh0[wrow * HH + k];
                } else if (rokA) {
                    if (k < HH)                      w = W_ih1[wrow * HH + k];
                    else if (k >= 64 && k < 64 + HH) w = W_hh1[wrow * HH + (k - 64)];
                }
                short hi, lo; split_bf16(w, hi, lo);
                h8[j] = hi; l8[j] = lo;
            }
            fh[s][ks] = h8; fl[s][ks] = l8;
        }
        const int uC = 4 * tile + q;
        vC[s]  = sv && (uC < HH);
        uCs[s] = uC;
#pragma unroll
        for (int g = 0; g < 4; ++g) {
            int rg = g * HH + uC;
            if (cls == 0) {
                cc[s][g] = vC[s] ? (b_ih0[rg] + b_hh0[rg]) : 0.f;
                bw[s][g] = vC[s] ? W_ih0[rg] : 0.f;
            } else {
                cc[s][g] = vC[s] ? (b_ih1[rg] + b_hh1[rg]) : 0.f;
                bw[s][g] = 0.f;
            }
        }
        widx[s] = ((uC >> 5) * 64 + ((uC >> 3) & 3) * 16 + m) * 8 + (uC & 7)
                  + cls * 1024;       // h2 slots (k=64+u) live +1024 shorts up
    }

    __syncthreads();

    // ---------------- time loop: ONE barrier per iteration ----------------
    for (int tt = 0; tt <= TT; ++tt) {
        const int p = tt & 1;

        if (cls == 0) {
            if (tt < TT) {            // layer 0, t = tt -> h1(tt) into buf p^1
                const float xv = xs[tt * BT + m];
                floatx4 acc[4];
#pragma unroll
                for (int s = 0; s < 4; ++s)
#pragma unroll
                    for (int g = 0; g < 4; ++g)
                        acc[s][g] = cc[s][g] + bw[s][g] * xv;
#pragma unroll
                for (int ks = 0; ks < 2; ++ks) {
                    short8 bh = *(const short8*)&Hhi[p][(ks * 64 + ln) * 8];
                    short8 bl = *(const short8*)&Hlo[p][(ks * 64 + ln) * 8];
#pragma unroll
                    for (int s = 0; s < 3; ++s) {
                        acc[s] = MFMA(fh[s][ks], bh, acc[s]);
                        acc[s] = MFMA(fh[s][ks], bl, acc[s]);
                        acc[s] = MFMA(fl[s][ks], bh, acc[s]);
                    }
                    if (wl == 0) {
                        acc[3] = MFMA(fh[3][ks], bh, acc[3]);
                        acc[3] = MFMA(fh[3][ks], bl, acc[3]);
                        acc[3] = MFMA(fl[3][ks], bh, acc[3]);
                    }
                }
#pragma unroll
                for (int s = 0; s < 4; ++s) {
                    if (s == 3 && wl != 0) continue;    // wave-uniform skip
                    if (vC[s]) {
                        float c = fast_sig(acc[s][1]) * cst[s]
                                + fast_sig(acc[s][0]) * fast_tanh(acc[s][2]);
                        cst[s] = c;
                        float h = fast_sig(acc[s][3]) * fast_tanh(c);
                        short hi, lo; split_bf16(h, hi, lo);
                        Hhi[p ^ 1][widx[s]] = hi; Hlo[p ^ 1][widx[s]] = lo;
                    }
                }
            }
        } else {
            if (tt > 0) {             // layer 1, t = tt-1 -> h2(tt-1) into buf p^1
                floatx4 acc[4];
#pragma unroll
                for (int s = 0; s < 4; ++s)
#pragma unroll
                    for (int g = 0; g < 4; ++g)
                        acc[s][g] = cc[s][g];
#pragma unroll
                for (int ks = 0; ks < 4; ++ks) {
                    short8 bh = *(const short8*)&Hhi[p][(ks * 64 + ln) * 8];
                    short8 bl = *(const short8*)&Hlo[p][(ks * 64 + ln) * 8];
#pragma unroll
                    for (int s = 0; s < 3; ++s) {
                        acc[s] = MFMA(fh[s][ks], bh, acc[s]);
                        acc[s] = MFMA(fh[s][ks], bl, acc[s]);
                        acc[s] = MFMA(fl[s][ks], bh, acc[s]);
                    }
                    if (wl == 0) {
                        acc[3] = MFMA(fh[3][ks], bh, acc[3]);
                        acc[3] = MFMA(fh[3][ks], bl, acc[3]);
                        acc[3] = MFMA(fl[3][ks], bh, acc[3]);
                    }
                }
#pragma unroll
                for (int s = 0; s < 4; ++s) {
                    if (s == 3 && wl != 0) continue;    // wave-uniform skip
                    if (vC[s]) {
                        float c = fast_sig(acc[s][1]) * cst[s]
                                + fast_sig(acc[s][0]) * fast_tanh(acc[s][2]);
                        cst[s] = c;
                        float h = fast_sig(acc[s][3]) * fast_tanh(c);
                        short hi, lo; split_bf16(h, hi, lo);
                        Hhi[p ^ 1][widx[s]] = hi; Hlo[p ^ 1][widx[s]] = lo;
                        if (tt == TT) h2f[m * HH + uCs[s]] = h;
                    }
                }
            }
        }

        __syncthreads();   // buf p^1 writes visible for iteration tt+1
    }

    // ---------------- FC epilogue ----------------
    if (tid < BT) {
        float a = b_fc[0];
        for (int u = 0; u < HH; ++u)
            a = fmaf(h2f[tid * HH + u], W_fc[u], a);
        out[b0g + tid] = a;
    }
}

extern "C" void kernel_launch(void* const* d_in, const int* in_sizes, int n_in,
                              void* d_out, int out_size, void* d_ws, size_t ws_size,
                              hipStream_t stream) {
    const float* x     = (const float*)d_in[0];
    const float* W_ih0 = (const float*)d_in[1];
    const float* W_hh0 = (const float*)d_in[2];
    const float* b_ih0 = (const float*)d_in[3];
    const float* b_hh0 = (const float*)d_in[4];
    const float* W_ih1 = (const float*)d_in[5];
    const float* W_hh1 = (const float*)d_in[6];
    const float* b_ih1 = (const float*)d_in[7];
    const float* b_hh1 = (const float*)d_in[8];
    const float* W_fc  = (const float*)d_in[9];
    const float* b_fc  = (const float*)d_in[10];
    float* out = (float*)d_out;

    dim3 grid(4096 / BT);   // 256 blocks = 1/CU
    dim3 block(512);        // 8 waves: 4 layer-0 + 4 layer-1
    lstm_mfma<<<grid, block, 0, stream>>>(x, W_ih0, W_hh0, b_ih0, b_hh0,
                                          W_ih1, W_hh1, b_ih1, b_hh1,
                                          W_fc, b_fc, out);
}

// Round 6
// 635.682 us; speedup vs baseline: 1.0913x; 1.0913x over previous
//
#include <hip/hip_runtime.h>

// 2-layer LSTM (H=50, B=4096, T=512, D_in=1) + FC(50->1), fused MFMA, round 6.
//
// 256 blocks (1/CU) x 832 threads (13 waves), 16 batches/block, all 512 steps.
// v_mfma_f32_16x16x32_bf16, hi/lo bf16 split, 3 products (~fp32 accuracy).
//
// KEY CHANGE vs r4/r5: 13 waves, BALANCED PAIRING. Wave w owns the pair
// (L0 tile w, L1 tile w) -> every wave: 18 MFMAs + 2 cell updates. No dummy
// tiles (r4 ran 16 padded tiles = 288 MFMA/CU-iter; now 13 real = 234), no
// class imbalance (r5's regression: barrier waits for the heaviest wave).
// 3-4 waves/SIMD (vs r4's 2) doubles latency hiding of the post-barrier
// read-burst -> MFMA-chain -> trans-chain serial path.
//
// Gate-interleaved row permutation (r4-verified): packed row 4u+g -> lane
// (q,m) of tile T holds all 4 gates of unit 4T+q, batch m, in its acc regs;
// cell update is in-register; h written straight to B-frag LDS (2-byte).
// B-frag layout (r2-r5-verified): k -> ks=k>>5, lane=((k>>3)&3)*16+n, j=k&7.
// Double-buffered H on parity tt&1; ONE barrier per iteration.
// Schedule: iter tt computes L0(t=tt) and L1(t=tt-1) from one Hcat snapshot
// [h1(tt-1) | h2(tt-2)] in buffer p; writes h1(tt), h2(tt-1) to buffer p^1.

#define TT 512
#define HH 50
#define BT 16
#define NTHR 832   // 13 waves

typedef short short8 __attribute__((ext_vector_type(8)));
typedef float floatx4 __attribute__((ext_vector_type(4)));

static __device__ __forceinline__ float fast_sig(float x) {
    float e = __builtin_amdgcn_exp2f(x * -1.44269504f);   // exp(-x)
    return __builtin_amdgcn_rcpf(1.0f + e);
}
static __device__ __forceinline__ float fast_tanh(float x) {
    float e = __builtin_amdgcn_exp2f(x * -2.88539008f);   // exp(-2x)
    return __builtin_amdgcn_rcpf(1.0f + e) * 2.0f - 1.0f;
}
static __device__ __forceinline__ void split_bf16(float x, short& hi, short& lo) {
    unsigned u = __float_as_uint(x);
    hi = (short)(u >> 16);
    float xh = __uint_as_float(u & 0xffff0000u);
    lo = (short)(__float_as_uint(x - xh) >> 16);
}
#define MFMA(a, b, c) __builtin_amdgcn_mfma_f32_16x16x32_bf16((a), (b), (c), 0, 0, 0)

__global__ __launch_bounds__(NTHR, 4) void lstm_mfma(
    const float* __restrict__ x,
    const float* __restrict__ W_ih0, const float* __restrict__ W_hh0,
    const float* __restrict__ b_ih0, const float* __restrict__ b_hh0,
    const float* __restrict__ W_ih1, const float* __restrict__ W_hh1,
    const float* __restrict__ b_ih1, const float* __restrict__ b_hh1,
    const float* __restrict__ W_fc,  const float* __restrict__ b_fc,
    float* __restrict__ out)
{
    __shared__ __align__(16) short Hhi[2][2048];   // [buf][(ks*64+lane)*8+j]
    __shared__ __align__(16) short Hlo[2][2048];
    __shared__ float xs[TT * BT];
    __shared__ float h2f[BT * HH];

    const int tid = threadIdx.x;
    const int ln  = tid & 63;
    const int wv  = tid >> 6;         // wave 0..12 == tile index for BOTH layers
    const int m   = ln & 15;          // batch col (A row-in-tile, C col)
    const int q   = ln >> 4;          // quad (A k-group, C row-group)
    const int b0g = blockIdx.x * BT;

    // ---------------- one-time init ----------------
    for (int i = tid; i < BT * TT; i += NTHR) {
        int b = i & 15, t = i >> 4;
        xs[t * BT + b] = x[(size_t)(b0g + b) * TT + t];
    }
    for (int i = tid; i < 2 * 2048; i += NTHR) {
        ((short*)Hhi)[i] = 0; ((short*)Hlo)[i] = 0;
    }

    // ---- A-fragments for this wave's tile (compile-time indexed) ----
    // A-lane (q,m) supplies packed row pr = wv*16 + m: unit uA = 4*wv + (m>>2),
    // gate gA = m&3 -> original W row = gA*50 + uA; k = ks*32 + q*8 + j.
    const int  uA   = 4 * wv + (m >> 2);
    const int  gA   = m & 3;
    const bool rokA = (uA < HH);
    const int  wrow = gA * HH + uA;

    short8 a0h[2], a0l[2];            // layer-0 (W_hh0), ks 0..1
    short8 a1h[4], a1l[4];            // layer-1 ([W_ih1|pad|W_hh1|pad]), ks 0..3
#pragma unroll
    for (int ks = 0; ks < 2; ++ks) {
        short8 h8, l8;
#pragma unroll
        for (int j = 0; j < 8; ++j) {
            int k = ks * 32 + q * 8 + j;
            float w = (rokA && k < HH) ? W_hh0[wrow * HH + k] : 0.f;
            short hi, lo; split_bf16(w, hi, lo);
            h8[j] = hi; l8[j] = lo;
        }
        a0h[ks] = h8; a0l[ks] = l8;
    }
#pragma unroll
    for (int ks = 0; ks < 4; ++ks) {
        short8 h8, l8;
#pragma unroll
        for (int j = 0; j < 8; ++j) {
            int k = ks * 32 + q * 8 + j;
            float w = 0.f;
            if (rokA) {
                if (k < HH)                      w = W_ih1[wrow * HH + k];
                else if (k >= 64 && k < 64 + HH) w = W_hh1[wrow * HH + (k - 64)];
            }
            short hi, lo; split_bf16(w, hi, lo);
            h8[j] = hi; l8[j] = lo;
        }
        a1h[ks] = h8; a1l[ks] = l8;
    }

    // ---- C-lane constants: unit uC = 4*wv + q, batch m, gate g = reg ----
    const int  uC = 4 * wv + q;
    const bool vC = (uC < HH);
    float cc0[4], bw0[4], cc1[4];
#pragma unroll
    for (int g = 0; g < 4; ++g) {
        int rg = g * HH + uC;
        cc0[g] = vC ? (b_ih0[rg] + b_hh0[rg]) : 0.f;
        bw0[g] = vC ? W_ih0[rg] : 0.f;
        cc1[g] = vC ? (b_ih1[rg] + b_hh1[rg]) : 0.f;
    }
    const int widx = ((uC >> 5) * 64 + ((uC >> 3) & 3) * 16 + m) * 8 + (uC & 7);
    float c1 = 0.f, c2 = 0.f;         // cell states (layer 0, layer 1)

    __syncthreads();

    // ---------------- time loop: ONE barrier per iteration ----------------
    for (int tt = 0; tt <= TT; ++tt) {
        const int p = tt & 1;

        // Hcat snapshot (buf p): 8 x ds_read_b128
        short8 bh[4], bl[4];
#pragma unroll
        for (int ks = 0; ks < 4; ++ks) {
            bh[ks] = *(const short8*)&Hhi[p][(ks * 64 + ln) * 8];
            bl[ks] = *(const short8*)&Hlo[p][(ks * 64 + ln) * 8];
        }

        // ---- layer 0, t = tt -> h1(tt) into buf p^1 ----
        if (tt < TT) {
            const float xv = xs[tt * BT + m];
            floatx4 acc;
#pragma unroll
            for (int g = 0; g < 4; ++g) acc[g] = cc0[g] + bw0[g] * xv;
#pragma unroll
            for (int ks = 0; ks < 2; ++ks) {
                acc = MFMA(a0h[ks], bh[ks], acc);
                acc = MFMA(a0h[ks], bl[ks], acc);
                acc = MFMA(a0l[ks], bh[ks], acc);
            }
            if (vC) {
                float c = fast_sig(acc[1]) * c1 + fast_sig(acc[0]) * fast_tanh(acc[2]);
                c1 = c;
                float h = fast_sig(acc[3]) * fast_tanh(c);
                short hi, lo; split_bf16(h, hi, lo);
                Hhi[p ^ 1][widx] = hi; Hlo[p ^ 1][widx] = lo;
            }
        }

        // ---- layer 1, t = tt-1 -> h2(tt-1) into buf p^1 ----
        if (tt > 0) {
            floatx4 acc;
#pragma unroll
            for (int g = 0; g < 4; ++g) acc[g] = cc1[g];
#pragma unroll
            for (int ks = 0; ks < 4; ++ks) {
                acc = MFMA(a1h[ks], bh[ks], acc);
                acc = MFMA(a1h[ks], bl[ks], acc);
                acc = MFMA(a1l[ks], bh[ks], acc);
            }
            if (vC) {
                float c = fast_sig(acc[1]) * c2 + fast_sig(acc[0]) * fast_tanh(acc[2]);
                c2 = c;
                float h = fast_sig(acc[3]) * fast_tanh(c);
                short hi, lo; split_bf16(h, hi, lo);
                Hhi[p ^ 1][widx + 1024] = hi; Hlo[p ^ 1][widx + 1024] = lo;
                if (tt == TT) h2f[m * HH + uC] = h;
            }
        }

        __syncthreads();   // buf p^1 writes visible for iteration tt+1
    }

    // ---------------- FC epilogue ----------------
    if (tid < BT) {
        float a = b_fc[0];
        for (int u = 0; u < HH; ++u)
            a = fmaf(h2f[tid * HH + u], W_fc[u], a);
        out[b0g + tid] = a;
    }
}

extern "C" void kernel_launch(void* const* d_in, const int* in_sizes, int n_in,
                              void* d_out, int out_size, void* d_ws, size_t ws_size,
                              hipStream_t stream) {
    const float* x     = (const float*)d_in[0];
    const float* W_ih0 = (const float*)d_in[1];
    const float* W_hh0 = (const float*)d_in[2];
    const float* b_ih0 = (const float*)d_in[3];
    const float* b_hh0 = (const float*)d_in[4];
    const float* W_ih1 = (const float*)d_in[5];
    const float* W_hh1 = (const float*)d_in[6];
    const float* b_ih1 = (const float*)d_in[7];
    const float* b_hh1 = (const float*)d_in[8];
    const float* W_fc  = (const float*)d_in[9];
    const float* b_fc  = (const float*)d_in[10];
    float* out = (float*)d_out;

    dim3 grid(4096 / BT);   // 256 blocks = 1/CU
    dim3 block(NTHR);       // 13 waves: wave w = tile w, both layers
    lstm_mfma<<<grid, block, 0, stream>>>(x, W_ih0, W_hh0, b_ih0, b_hh0,
                                          W_ih1, W_hh1, b_ih1, b_hh1,
                                          W_fc, b_fc, out);
}

// Round 7
// 627.244 us; speedup vs baseline: 1.1060x; 1.0135x over previous
//
#include <hip/hip_runtime.h>

// 2-layer LSTM (H=50, B=4096, T=512, D_in=1) + FC(50->1), fused MFMA, round 7.
//
// Structure locked from r6 (13 waves x 1 tile, BT=16, 1 block/CU, 1 barrier/step,
// in-lane cell update, bf16 hi/lo 3-product). This round: VALU diet.
//  - fused cell math: 5 exp + 3 rcp (was 10 trans) with c-clamp for NaN safety
//  - manual 2x unroll, compile-time buffer parity, peeled tt=0 / 511 / 512
//  - no divergent branches in the loop; unconditional h-writes (garbage units
//    50/51 land in zero-weight K slots); epilogue reads h2 from B-frag LDS
//  - round-to-nearest bf16 splits (weights & h): dropped Al*Bl term 2^-16 -> 2^-18
// B-frag layout (r2-r6-verified): k -> ks=k>>5, lane=((k>>3)&3)*16+n, j=k&7.
// Gate-permuted A rows (r4-verified): packed row 4u+g -> lane (q,m) of tile w
// holds all 4 gates of unit 4w+q, batch m, in its 4 acc regs.

#define TT 512
#define HH 50
#define BT 16
#define NTHR 832   // 13 waves
#define L2E 1.44269504f

typedef short short8 __attribute__((ext_vector_type(8)));
typedef float floatx4 __attribute__((ext_vector_type(4)));

static __device__ __forceinline__ float fexp2(float x) { return __builtin_amdgcn_exp2f(x); }
static __device__ __forceinline__ float frcp(float x)  { return __builtin_amdgcn_rcpf(x); }

// fused LSTM cell: c' = sig(gf)*c + sig(gi)*tanh(gg); returns h = sig(go)*tanh(c').
// 5 exp + 3 rcp. c clamped before tanh-exp so (1-E)*rcp(inf) can't make NaN.
static __device__ __forceinline__ float cell_update(float gi, float gf, float gg,
                                                    float go, float& c) {
    float Ei  = fexp2(gi * -L2E);
    float Eg  = fexp2(gg * (-2.0f * L2E));
    float Ef  = fexp2(gf * -L2E);
    float Rig = frcp((1.0f + Ei) * (1.0f + Eg));
    float Rf  = frcp(1.0f + Ef);
    c = c * Rf + (1.0f - Eg) * Rig;
    float cl = fminf(fmaxf(c, -18.0f), 18.0f);
    float Eo = fexp2(go * -L2E);
    float Ec = fexp2(cl * (-2.0f * L2E));
    float R  = frcp((1.0f + Eo) * (1.0f + Ec));
    return (1.0f - Ec) * R;
}

// round-to-nearest-even bf16 hi/lo split
static __device__ __forceinline__ void split_rn(float x, short& hi, short& lo) {
    unsigned u  = __float_as_uint(x);
    unsigned rh = (u + 0x7FFFu + ((u >> 16) & 1u)) & 0xFFFF0000u;
    hi = (short)(rh >> 16);
    float res = x - __uint_as_float(rh);
    unsigned u2 = __float_as_uint(res);
    unsigned rl = u2 + 0x7FFFu + ((u2 >> 16) & 1u);
    lo = (short)(rl >> 16);
}

#define MFMA(a, b, c) __builtin_amdgcn_mfma_f32_16x16x32_bf16((a), (b), (c), 0, 0, 0)

__global__ __launch_bounds__(NTHR, 4) void lstm_mfma(
    const float* __restrict__ x,
    const float* __restrict__ W_ih0, const float* __restrict__ W_hh0,
    const float* __restrict__ b_ih0, const float* __restrict__ b_hh0,
    const float* __restrict__ W_ih1, const float* __restrict__ W_hh1,
    const float* __restrict__ b_ih1, const float* __restrict__ b_hh1,
    const float* __restrict__ W_fc,  const float* __restrict__ b_fc,
    float* __restrict__ out)
{
    __shared__ __align__(16) short Hhi[2][2048];   // [buf][(ks*64+lane)*8+j]
    __shared__ __align__(16) short Hlo[2][2048];
    __shared__ float xs[TT * BT];

    const int tid = threadIdx.x;
    const int ln  = tid & 63;
    const int wv  = tid >> 6;         // wave 0..12 == tile index (both layers)
    const int m   = ln & 15;          // batch col
    const int q   = ln >> 4;          // quad
    const int b0g = blockIdx.x * BT;

    // ---------------- one-time init ----------------
    for (int i = tid; i < BT * TT; i += NTHR) {
        int b = i & 15, t = i >> 4;
        xs[t * BT + b] = x[(size_t)(b0g + b) * TT + t];
    }
    for (int i = tid; i < 2 * 2048; i += NTHR) {
        ((short*)Hhi)[i] = 0; ((short*)Hlo)[i] = 0;
    }

    // ---- A-fragments (gate-permuted rows), RN splits ----
    const int  uA   = 4 * wv + (m >> 2);
    const int  gA   = m & 3;
    const bool rokA = (uA < HH);
    const int  wrow = gA * HH + uA;

    short8 a0h[2], a0l[2];            // layer-0 (W_hh0), ks 0..1
    short8 a1h[4], a1l[4];            // layer-1 ([W_ih1|pad|W_hh1|pad]), ks 0..3
#pragma unroll
    for (int ks = 0; ks < 2; ++ks) {
        short8 h8, l8;
#pragma unroll
        for (int j = 0; j < 8; ++j) {
            int k = ks * 32 + q * 8 + j;
            float w = (rokA && k < HH) ? W_hh0[wrow * HH + k] : 0.f;
            short hi, lo; split_rn(w, hi, lo);
            h8[j] = hi; l8[j] = lo;
        }
        a0h[ks] = h8; a0l[ks] = l8;
    }
#pragma unroll
    for (int ks = 0; ks < 4; ++ks) {
        short8 h8, l8;
#pragma unroll
        for (int j = 0; j < 8; ++j) {
            int k = ks * 32 + q * 8 + j;
            float w = 0.f;
            if (rokA) {
                if (k < HH)                      w = W_ih1[wrow * HH + k];
                else if (k >= 64 && k < 64 + HH) w = W_hh1[wrow * HH + (k - 64)];
            }
            short hi, lo; split_rn(w, hi, lo);
            h8[j] = hi; l8[j] = lo;
        }
        a1h[ks] = h8; a1l[ks] = l8;
    }

    // ---- C-lane constants: unit uC = 4*wv + q, batch m, gate g = reg ----
    const int  uC = 4 * wv + q;       // 50,51 for wave 12 q>=2: dummy (zero-wt slots)
    const bool vC = (uC < HH);
    float cc0[4], bw0[4], cc1[4];
#pragma unroll
    for (int g = 0; g < 4; ++g) {
        int rg = g * HH + (vC ? uC : 0);
        cc0[g] = vC ? (b_ih0[rg] + b_hh0[rg]) : 0.f;
        bw0[g] = vC ? W_ih0[rg] : 0.f;
        cc1[g] = vC ? (b_ih1[rg] + b_hh1[rg]) : 0.f;
    }
    const int kh = uC & 63;           // h1 slot k (50/51 dummies land in zero-wt K)
    const int widx = ((kh >> 5) * 64 + ((kh >> 3) & 3) * 16 + m) * 8 + (kh & 7);
    float c1 = 0.f, c2 = 0.f;

    __syncthreads();

    // one full iteration: read snapshot buf P, L0(t=ttv) if DO_L0, L1(t=ttv-1),
    // write h into buf P^1, barrier. P is compile-time.
#define ITER(ttv, P, DO_L0)                                               \
    {                                                                     \
        short8 bh[4], bl[4];                                              \
        _Pragma("unroll")                                                 \
        for (int ks = 0; ks < 4; ++ks) {                                  \
            bh[ks] = *(const short8*)&Hhi[(P)][(ks * 64 + ln) * 8];       \
            bl[ks] = *(const short8*)&Hlo[(P)][(ks * 64 + ln) * 8];       \
        }                                                                 \
        if (DO_L0) {                                                      \
            const float xv = xs[(ttv) * BT + m];                          \
            floatx4 acc;                                                  \
            _Pragma("unroll")                                             \
            for (int g = 0; g < 4; ++g) acc[g] = cc0[g] + bw0[g] * xv;    \
            _Pragma("unroll")                                             \
            for (int ks = 0; ks < 2; ++ks) {                              \
                acc = MFMA(a0h[ks], bh[ks], acc);                         \
                acc = MFMA(a0h[ks], bl[ks], acc);                         \
                acc = MFMA(a0l[ks], bh[ks], acc);                         \
            }                                                             \
            float h = cell_update(acc[0], acc[1], acc[2], acc[3], c1);    \
            short hi, lo; split_rn(h, hi, lo);                            \
            Hhi[(P) ^ 1][widx] = hi; Hlo[(P) ^ 1][widx] = lo;             \
        }                                                                 \
        {                                                                 \
            floatx4 acc;                                                  \
            _Pragma("unroll")                                             \
            for (int g = 0; g < 4; ++g) acc[g] = cc1[g];                  \
            _Pragma("unroll")                                             \
            for (int ks = 0; ks < 4; ++ks) {                              \
                acc = MFMA(a1h[ks], bh[ks], acc);                         \
                acc = MFMA(a1h[ks], bl[ks], acc);                         \
                acc = MFMA(a1l[ks], bh[ks], acc);                         \
            }                                                             \
            float h = cell_update(acc[0], acc[1], acc[2], acc[3], c2);    \
            short hi, lo; split_rn(h, hi, lo);                            \
            Hhi[(P) ^ 1][widx + 1024] = hi; Hlo[(P) ^ 1][widx + 1024] = lo; \
        }                                                                 \
        __syncthreads();                                                  \
    }

    // ---- tt = 0 (p=0): h=0 -> L0 needs no MFMA; h2(-1)=0 already in buf 1 ----
    {
        const float xv = xs[m];       // t=0
        float h = cell_update(cc0[0] + bw0[0] * xv, cc0[1] + bw0[1] * xv,
                              cc0[2] + bw0[2] * xv, cc0[3] + bw0[3] * xv, c1);
        short hi, lo; split_rn(h, hi, lo);
        Hhi[1][widx] = hi; Hlo[1][widx] = lo;
        __syncthreads();
    }

    // ---- steady state: pairs (2k-1 [p=1], 2k [p=0]) for k = 1..255 ----
    for (int k = 1; k <= 255; ++k) {
        ITER(2 * k - 1, 1, true);
        ITER(2 * k,     0, true);
    }
    // ---- tail: tt = 511 (p=1, both), tt = 512 (p=0, L1 only) ----
    ITER(511, 1, true);
    ITER(512, 0, false);

    // ---------------- FC epilogue: h2(511) lives in buf 1, slots k=64+u ----------------
    if (tid < BT) {
        float a = b_fc[0];
        for (int u = 0; u < HH; ++u) {
            int k = 64 + u;
            int idx = ((k >> 5) * 64 + ((k >> 3) & 3) * 16 + tid) * 8 + (k & 7);
            float hv = __uint_as_float(((unsigned)(unsigned short)Hhi[1][idx]) << 16)
                     + __uint_as_float(((unsigned)(unsigned short)Hlo[1][idx]) << 16);
            a = fmaf(hv, W_fc[u], a);
        }
        out[b0g + tid] = a;
    }
#undef ITER
}

extern "C" void kernel_launch(void* const* d_in, const int* in_sizes, int n_in,
                              void* d_out, int out_size, void* d_ws, size_t ws_size,
                              hipStream_t stream) {
    const float* x     = (const float*)d_in[0];
    const float* W_ih0 = (const float*)d_in[1];
    const float* W_hh0 = (const float*)d_in[2];
    const float* b_ih0 = (const float*)d_in[3];
    const float* b_hh0 = (const float*)d_in[4];
    const float* W_ih1 = (const float*)d_in[5];
    const float* W_hh1 = (const float*)d_in[6];
    const float* b_ih1 = (const float*)d_in[7];
    const float* b_hh1 = (const float*)d_in[8];
    const float* W_fc  = (const float*)d_in[9];
    const float* b_fc  = (const float*)d_in[10];
    float* out = (float*)d_out;

    dim3 grid(4096 / BT);   // 256 blocks = 1/CU
    dim3 block(NTHR);       // 13 waves
    lstm_mfma<<<grid, block, 0, stream>>>(x, W_ih0, W_hh0, b_ih0, b_hh0,
                                          W_ih1, W_hh1, b_ih1, b_hh1,
                                          W_fc, b_fc, out);
}

// Round 8
// 523.472 us; speedup vs baseline: 1.3252x; 1.1982x over previous
//
#include <hip/hip_runtime.h>

// 2-layer LSTM (H=50, B=4096, T=512, D_in=1) + FC(50->1), fused MFMA, round 8.
//
// Structure from r6/r7 (13 waves x 1 tile, BT=16, 1 block/CU, 1 barrier/step,
// gate-permuted rows, in-lane cell update). KEY CHANGE: f16 2-product.
//   - mfma_f32_16x16x32_f16; weights held as f16 hi + f16 lo (2 products ->
//     weight error 2^-22, negligible); h stored as ONE RN f16 (rel err 2^-11,
//     unbiased). r7's absmax=0.0 showed the precision budget is under-spent.
//   - Hcat reads halve: 4 ds_read_b128 per wave-iter (was 8). LDS pipe
//     ~1650 -> ~840 cyc/CU-iter. MFMA 18 -> 12. h-writes 4 -> 2 (ds_write_b16).
//   - split_rn replaced by one v_cvt_f16_f32.
//   - ITER ordered so L0 math overlaps the ks2-3 reads.
// B-frag layout (r2-r7-verified, dtype-independent): k -> ks=k>>5,
// lane=((k>>3)&3)*16+n, j=k&7; read = b128 @ lane*16.
// Fallback if absmax > 5.9e-3: revert to bf16 3-product (r7 numerics).

#define TT 512
#define HH 50
#define BT 16
#define NTHR 832   // 13 waves
#define L2E 1.44269504f

typedef _Float16 half8 __attribute__((ext_vector_type(8)));
typedef float floatx4 __attribute__((ext_vector_type(4)));

static __device__ __forceinline__ float fexp2(float x) { return __builtin_amdgcn_exp2f(x); }
static __device__ __forceinline__ float frcp(float x)  { return __builtin_amdgcn_rcpf(x); }

// fused LSTM cell: c' = sig(gf)*c + sig(gi)*tanh(gg); returns h = sig(go)*tanh(c').
// 5 exp + 3 rcp; c clamped before the tanh-exp so rcp(inf) can't NaN.
static __device__ __forceinline__ float cell_update(float gi, float gf, float gg,
                                                    float go, float& c) {
    float Ei  = fexp2(gi * -L2E);
    float Eg  = fexp2(gg * (-2.0f * L2E));
    float Ef  = fexp2(gf * -L2E);
    float Rig = frcp((1.0f + Ei) * (1.0f + Eg));
    float Rf  = frcp(1.0f + Ef);
    c = c * Rf + (1.0f - Eg) * Rig;
    float cl = fminf(fmaxf(c, -18.0f), 18.0f);
    float Eo = fexp2(go * -L2E);
    float Ec = fexp2(cl * (-2.0f * L2E));
    float R  = frcp((1.0f + Eo) * (1.0f + Ec));
    return (1.0f - Ec) * R;
}

#define MFMA(a, b, c) __builtin_amdgcn_mfma_f32_16x16x32_f16((a), (b), (c), 0, 0, 0)

__global__ __launch_bounds__(NTHR, 4) void lstm_mfma(
    const float* __restrict__ x,
    const float* __restrict__ W_ih0, const float* __restrict__ W_hh0,
    const float* __restrict__ b_ih0, const float* __restrict__ b_hh0,
    const float* __restrict__ W_ih1, const float* __restrict__ W_hh1,
    const float* __restrict__ b_ih1, const float* __restrict__ b_hh1,
    const float* __restrict__ W_fc,  const float* __restrict__ b_fc,
    float* __restrict__ out)
{
    __shared__ __align__(16) _Float16 Hf[2][2048];   // [buf][(ks*64+lane)*8+j]
    __shared__ float xs[TT * BT];

    const int tid = threadIdx.x;
    const int ln  = tid & 63;
    const int wv  = tid >> 6;         // wave 0..12 == tile index (both layers)
    const int m   = ln & 15;          // batch col
    const int q   = ln >> 4;          // quad
    const int b0g = blockIdx.x * BT;

    // ---------------- one-time init ----------------
    for (int i = tid; i < BT * TT; i += NTHR) {
        int b = i & 15, t = i >> 4;
        xs[t * BT + b] = x[(size_t)(b0g + b) * TT + t];
    }
    for (int i = tid; i < 2 * 2048; i += NTHR) ((_Float16*)Hf)[i] = (_Float16)0.f;

    // ---- A-fragments (gate-permuted rows), f16 hi/lo ----
    const int  uA   = 4 * wv + (m >> 2);
    const int  gA   = m & 3;
    const bool rokA = (uA < HH);
    const int  wrow = gA * HH + uA;

    half8 a0h[2], a0l[2];             // layer-0 (W_hh0), ks 0..1
    half8 a1h[4], a1l[4];             // layer-1 ([W_ih1|pad|W_hh1|pad]), ks 0..3
#pragma unroll
    for (int ks = 0; ks < 2; ++ks) {
        half8 h8, l8;
#pragma unroll
        for (int j = 0; j < 8; ++j) {
            int k = ks * 32 + q * 8 + j;
            float w = (rokA && k < HH) ? W_hh0[wrow * HH + k] : 0.f;
            _Float16 wh = (_Float16)w;
            _Float16 wl = (_Float16)(w - (float)wh);
            h8[j] = wh; l8[j] = wl;
        }
        a0h[ks] = h8; a0l[ks] = l8;
    }
#pragma unroll
    for (int ks = 0; ks < 4; ++ks) {
        half8 h8, l8;
#pragma unroll
        for (int j = 0; j < 8; ++j) {
            int k = ks * 32 + q * 8 + j;
            float w = 0.f;
            if (rokA) {
                if (k < HH)                      w = W_ih1[wrow * HH + k];
                else if (k >= 64 && k < 64 + HH) w = W_hh1[wrow * HH + (k - 64)];
            }
            _Float16 wh = (_Float16)w;
            _Float16 wl = (_Float16)(w - (float)wh);
            h8[j] = wh; l8[j] = wl;
        }
        a1h[ks] = h8; a1l[ks] = l8;
    }

    // ---- C-lane constants: unit uC = 4*wv + q, batch m, gate g = reg ----
    const int  uC = 4 * wv + q;       // 50,51 (wave 12, q>=2): dummies -> zero-wt K slots
    const bool vC = (uC < HH);
    float cc0[4], bw0[4], cc1[4];
#pragma unroll
    for (int g = 0; g < 4; ++g) {
        int rg = g * HH + (vC ? uC : 0);
        cc0[g] = vC ? (b_ih0[rg] + b_hh0[rg]) : 0.f;
        bw0[g] = vC ? W_ih0[rg] : 0.f;
        cc1[g] = vC ? (b_ih1[rg] + b_hh1[rg]) : 0.f;
    }
    const int kh = uC & 63;           // dummy units 50/51 land in zero-weight K slots
    const int widx = ((kh >> 5) * 64 + ((kh >> 3) & 3) * 16 + m) * 8 + (kh & 7);
    float c1 = 0.f, c2 = 0.f;

    __syncthreads();

    // one iteration: snapshot buf P (compile-time), L0(t=ttv) if DO_L0,
    // L1(t=ttv-1), write h -> buf P^1, barrier. Reads split so L0's MFMAs
    // overlap the ks2-3 read latency.
#define ITER(ttv, P, DO_L0)                                               \
    {                                                                     \
        half8 b0 = *(const half8*)&Hf[(P)][(0 * 64 + ln) * 8];            \
        half8 b1 = *(const half8*)&Hf[(P)][(1 * 64 + ln) * 8];            \
        half8 b2 = *(const half8*)&Hf[(P)][(2 * 64 + ln) * 8];            \
        half8 b3 = *(const half8*)&Hf[(P)][(3 * 64 + ln) * 8];            \
        if (DO_L0) {                                                      \
            const float xv = xs[(ttv) * BT + m];                          \
            floatx4 acc;                                                  \
            _Pragma("unroll")                                             \
            for (int g = 0; g < 4; ++g) acc[g] = cc0[g] + bw0[g] * xv;    \
            acc = MFMA(a0h[0], b0, acc);                                  \
            acc = MFMA(a0l[0], b0, acc);                                  \
            acc = MFMA(a0h[1], b1, acc);                                  \
            acc = MFMA(a0l[1], b1, acc);                                  \
            float h = cell_update(acc[0], acc[1], acc[2], acc[3], c1);    \
            Hf[(P) ^ 1][widx] = (_Float16)h;                              \
        }                                                                 \
        {                                                                 \
            floatx4 acc;                                                  \
            _Pragma("unroll")                                             \
            for (int g = 0; g < 4; ++g) acc[g] = cc1[g];                  \
            acc = MFMA(a1h[0], b0, acc);                                  \
            acc = MFMA(a1l[0], b0, acc);                                  \
            acc = MFMA(a1h[1], b1, acc);                                  \
            acc = MFMA(a1l[1], b1, acc);                                  \
            acc = MFMA(a1h[2], b2, acc);                                  \
            acc = MFMA(a1l[2], b2, acc);                                  \
            acc = MFMA(a1h[3], b3, acc);                                  \
            acc = MFMA(a1l[3], b3, acc);                                  \
            float h = cell_update(acc[0], acc[1], acc[2], acc[3], c2);    \
            Hf[(P) ^ 1][widx + 1024] = (_Float16)h;                       \
        }                                                                 \
        __syncthreads();                                                  \
    }

    // ---- tt = 0 (p=0): h=0 -> L0 needs no MFMA; h2(-1)=0 already in buf 1 ----
    {
        const float xv = xs[m];
        float h = cell_update(cc0[0] + bw0[0] * xv, cc0[1] + bw0[1] * xv,
                              cc0[2] + bw0[2] * xv, cc0[3] + bw0[3] * xv, c1);
        Hf[1][widx] = (_Float16)h;
        __syncthreads();
    }

    // ---- steady state: pairs (2k-1 [p=1], 2k [p=0]) for k = 1..255 ----
    for (int k = 1; k <= 255; ++k) {
        ITER(2 * k - 1, 1, true);
        ITER(2 * k,     0, true);
    }
    // ---- tail: tt = 511 (p=1, both), tt = 512 (p=0, L1 only) ----
    ITER(511, 1, true);
    ITER(512, 0, false);

    // ---------------- FC epilogue: h2(511) in buf 1, slots k = 64+u ----------------
    if (tid < BT) {
        float a = b_fc[0];
        for (int u = 0; u < HH; ++u) {
            int k = 64 + u;
            int idx = ((k >> 5) * 64 + ((k >> 3) & 3) * 16 + tid) * 8 + (k & 7);
            a = fmaf((float)Hf[1][idx], W_fc[u], a);
        }
        out[b0g + tid] = a;
    }
#undef ITER
}

extern "C" void kernel_launch(void* const* d_in, const int* in_sizes, int n_in,
                              void* d_out, int out_size, void* d_ws, size_t ws_size,
                              hipStream_t stream) {
    const float* x     = (const float*)d_in[0];
    const float* W_ih0 = (const float*)d_in[1];
    const float* W_hh0 = (const float*)d_in[2];
    const float* b_ih0 = (const float*)d_in[3];
    const float* b_hh0 = (const float*)d_in[4];
    const float* W_ih1 = (const float*)d_in[5];
    const float* W_hh1 = (const float*)d_in[6];
    const float* b_ih1 = (const float*)d_in[7];
    const float* b_hh1 = (const float*)d_in[8];
    const float* W_fc  = (const float*)d_in[9];
    const float* b_fc  = (const float*)d_in[10];
    float* out = (float*)d_out;

    dim3 grid(4096 / BT);   // 256 blocks = 1/CU
    dim3 block(NTHR);       // 13 waves
    lstm_mfma<<<grid, block, 0, stream>>>(x, W_ih0, W_hh0, b_ih0, b_hh0,
                                          W_ih1, W_hh1, b_ih1, b_hh1,
                                          W_fc, b_fc, out);
}